// Round 18
// baseline (168.890 us; speedup 1.0000x reference)
//
#include <hip/hip_runtime.h>

#define NVV   778
#define NSEG  16
#define SEGSZ 49
#define GRIDN 32
#define BATCH 128
#define NPTS  784
#define VOLSZ (GRIDN * GRIDN * GRIDN)  // 32768 floats = 128 KB
#define NBLK  1024                      // 4 blocks/CU
#define VPB   4                         // volumes per block
#define PFLT  4096                      // floats per piece (4 slabs, 16 KB)

typedef float f4v __attribute__((ext_vector_type(4)));
#define NTLD(p) __builtin_nontemporal_load((const f4v*)(p))

// 16 KB piece staged by 2 producer waves (wv 0-1): 8 KB/wave, 8 x dwordx4
// nt loads (no L2/L3 allocation — R15's proven win).
#define STAGE(DST, SRC) { \
    const float* s_ = (SRC) + (wv << 11) + (lane << 2); \
    float*       d_ = (DST) + (wv << 11) + (lane << 2); \
    f4v c0 = NTLD(s_ + 0 * 256); \
    f4v c1 = NTLD(s_ + 1 * 256); \
    f4v c2 = NTLD(s_ + 2 * 256); \
    f4v c3 = NTLD(s_ + 3 * 256); \
    f4v c4 = NTLD(s_ + 4 * 256); \
    f4v c5 = NTLD(s_ + 5 * 256); \
    f4v c6 = NTLD(s_ + 6 * 256); \
    f4v c7 = NTLD(s_ + 7 * 256); \
    *(f4v*)(d_ + 0 * 256) = c0; \
    *(f4v*)(d_ + 1 * 256) = c1; \
    *(f4v*)(d_ + 2 * 256) = c2; \
    *(f4v*)(d_ + 3 * 256) = c3; \
    *(f4v*)(d_ + 4 * 256) = c4; \
    *(f4v*)(d_ + 5 * 256) = c5; \
    *(f4v*)(d_ + 6 * 256) = c6; \
    *(f4v*)(d_ + 7 * 256) = c7; }

// 2x2 xy-taps within one z-slab
__device__ __forceinline__ float tapxy(const float* slab, int x0, int y0,
                                       float wx, float wy)
{
    float s = 0.f;
    #pragma unroll
    for (int dy = 0; dy < 2; ++dy) {
        int yy = y0 + dy;
        if (yy < 0 || yy >= GRIDN) continue;
        float wyv = dy ? wy : 1.f - wy;
        const float* row = slab + yy * GRIDN;
        #pragma unroll
        for (int dx = 0; dx < 2; ++dx) {
            int xx = x0 + dx;
            if (xx < 0 || xx >= GRIDN) continue;
            s += wyv * (dx ? wx : 1.f - wx) * row[xx];
        }
    }
    return s;
}

// point J's taps landing in piece Q (slab s belongs to piece s>>2)
#define TAP1(Q, BASE, J) \
    if (a##J) { \
        if (z##J >= 0 && (z##J >> 2) == (Q)) \
            acc##J += (1.f - w##J##z) * tapxy((BASE) + (z##J - 4 * (Q)) * 1024, x##J, y##J, w##J##x, w##J##y); \
        if ((z##J + 1) <= 31 && ((z##J + 1) >> 2) == (Q)) \
            acc##J += w##J##z * tapxy((BASE) + (z##J + 1 - 4 * (Q)) * 1024, x##J, y##J, w##J##x, w##J##y); \
    }
#define TAPALL(Q, BASE) \
    TAP1(Q, BASE, 1) TAP1(Q, BASE, 2) \
    if (has3) { TAP1(Q, BASE, 3) }

#define SETUP(J, PX, PY, PZ) { \
    float fx = ((PX) - b4.x) * b4.w * 15.5f + 15.5f; \
    float fy = ((PY) - b4.y) * b4.w * 15.5f + 15.5f; \
    float fz = ((PZ) - b4.z) * b4.w * 15.5f + 15.5f; \
    a##J = (fx > -1.f && fx < 32.f && fy > -1.f && fy < 32.f && \
            fz > -1.f && fz < 32.f); \
    float xf = floorf(fx), yf = floorf(fy), zf = floorf(fz); \
    w##J##x = fx - xf; w##J##y = fy - yf; w##J##z = fz - zf; \
    x##J = (int)xf; y##J = (int)yf; z##J = (int)zf; acc##J = 0.f; }

// Persistent: 1024 blocks x 512 threads -> 4 independent blocks per CU
// (~33 KB LDS each, 32 waves/CU = max). Cross-block TLP at 4 streams/CU:
// any block's barrier drain is covered by 3 co-resident blocks. Waves
// 0-1 = producers (nt stage), waves 2-7 = consumers (2-3 points each,
// keeps VGPR under the 64 cap of 8 waves/EU). 8 phases/volume (16 KB
// pieces, globally alternating P0/P1), one deferred atomic per volume.
__global__ __launch_bounds__(512, 8) void sample_kernel(
    const float* __restrict__ vertices, const int* __restrict__ seg,
    const float* __restrict__ phiR, const float* __restrict__ phiL,
    float* __restrict__ loss)
{
    __shared__ __align__(16) float P0[PFLT];
    __shared__ __align__(16) float P1[PFLT];
    __shared__ float4 sbox[VPB];
    __shared__ float wsum[6];

    const int tid  = threadIdx.x;
    const int bx   = blockIdx.x;
    const int k    = bx & (NSEG - 1);    // constant per block (1024 % 16 == 0)
    const int wv   = tid >> 6;           // 0..1 producers, 2..7 consumers
    const int lane = tid & 63;
    const bool producer = (wv < 2);
    const int ct   = tid - 128;          // consumer thread id [0,384)

    auto phiPtr = [&](int it) {
        int vid  = bx + NBLK * it;
        int b    = (vid >> 4) & (BATCH - 1);
        int pass = vid >> 11;            // NSEG*BATCH = 2048
        return (pass == 0 ? phiR : phiL) + ((size_t)k * BATCH + b) * VOLSZ;
    };
    auto vertBase = [&](int it) {
        int vid  = bx + NBLK * it;
        int b    = (vid >> 4) & (BATCH - 1);
        int srcS = (vid >> 11) == 0 ? 1 : 0;   // pass0 samples LEFT verts
        return vertices + ((size_t)b * 2 + srcS) * NVV * 3;
    };
    auto bOf = [&](int it) { return ((bx + NBLK * it) >> 4) & (BATCH - 1); };

    // ---- prologue ----
    int pvi1 = 0, pvi2 = 0, pvi3 = 0;
    bool has3 = false;
    if (!producer) {
        pvi1 = seg[ct];
        pvi2 = seg[ct + 384];            // 383+384=767 < 784: always valid
        has3 = (ct + 768) < NPTS;        // ct < 16
        pvi3 = has3 ? seg[ct + 768] : 0;
    }

    // boxes: waves 0-3 compute the 4 volumes' boxes
    if (wv < VPB) {
        int vidw    = bx + NBLK * wv;
        int bbw     = (vidw >> 4) & (BATCH - 1);
        int boxSide = ((vidw >> 11) == 0) ? 0 : 1;   // opposite of sampled
        bool bact   = lane < SEGSZ;
        int bvi     = bact ? seg[k * SEGSZ + lane] : 0;
        const float* bvp = vertices + (((size_t)bbw * 2 + boxSide) * NVV + bvi) * 3;
        float x = bvp[0], y = bvp[1], z = bvp[2];
        float mnx = bact ? x : 1e30f, mxx = bact ? x : -1e30f;
        float mny = bact ? y : 1e30f, mxy = bact ? y : -1e30f;
        float mnz = bact ? z : 1e30f, mxz = bact ? z : -1e30f;
        #pragma unroll
        for (int m = 32; m; m >>= 1) {
            mnx = fminf(mnx, __shfl_xor(mnx, m));
            mxx = fmaxf(mxx, __shfl_xor(mxx, m));
            mny = fminf(mny, __shfl_xor(mny, m));
            mxy = fmaxf(mxy, __shfl_xor(mxy, m));
            mnz = fminf(mnz, __shfl_xor(mnz, m));
            mxz = fmaxf(mxz, __shfl_xor(mxz, m));
        }
        if (lane == 0) {
            float ext = fmaxf(fmaxf(mxx - mnx, mxy - mny), mxz - mnz);
            sbox[wv] = make_float4(0.5f * (mnx + mxx), 0.5f * (mny + mxy),
                                   0.5f * (mnz + mxz), 1.0f / (0.55f * ext));
        }
    }

    // volume-0 coords (consumers); producers stage piece 0 -> P0
    float p1x = 0.f, p1y = 0.f, p1z = 0.f, p2x = 0.f, p2y = 0.f, p2z = 0.f;
    float p3x = 0.f, p3y = 0.f, p3z = 0.f;
    if (producer) {
        STAGE(P0, phiPtr(0))
    } else {
        const float* vb = vertBase(0);
        p1x = vb[pvi1 * 3]; p1y = vb[pvi1 * 3 + 1]; p1z = vb[pvi1 * 3 + 2];
        p2x = vb[pvi2 * 3]; p2y = vb[pvi2 * 3 + 1]; p2z = vb[pvi2 * 3 + 2];
        if (has3) {
            p3x = vb[pvi3 * 3]; p3y = vb[pvi3 * 3 + 1]; p3z = vb[pvi3 * 3 + 2];
        }
    }
    __syncthreads();   // P0 resident; sbox visible

    float n1x = 0.f, n1y = 0.f, n1z = 0.f, n2x = 0.f, n2y = 0.f, n2z = 0.f;
    float n3x = 0.f, n3y = 0.f, n3z = 0.f;

    for (int v = 0; v < VPB; ++v) {
        const bool more = (v + 1 < VPB);
        bool a1 = false, a2 = false, a3 = false;
        int x1, y1, z1, x2, y2, z2, x3, y3, z3;
        float w1x, w1y, w1z, w2x, w2y, w2z, w3x, w3y, w3z;
        float acc1 = 0.f, acc2 = 0.f, acc3 = 0.f;

        #pragma unroll
        for (int q = 0; q < 8; ++q) {
            const float* tapbuf = (q & 1) ? P1 : P0;
            float*       stgbuf = (q & 1) ? P0 : P1;

            if (producer) {
                if (q < 7) {
                    STAGE(stgbuf, phiPtr(v) + (q + 1) * PFLT)
                } else if (more) {
                    STAGE(stgbuf, phiPtr(v + 1))
                }
            } else {
                if (q == 0) {
                    if (v > 0 && ct == 0) {   // deferred atomic for v-1
                        float tot = wsum[0] + wsum[1] + wsum[2] +
                                    wsum[3] + wsum[4] + wsum[5];
                        atomicAdd(loss + bOf(v - 1), tot * 0.25f);
                    }
                    float4 b4 = sbox[v];
                    SETUP(1, p1x, p1y, p1z)
                    SETUP(2, p2x, p2y, p2z)
                    if (has3) { SETUP(3, p3x, p3y, p3z) }
                }
                TAPALL(q, tapbuf)
                if (q == 6 && more) {         // next volume's coords
                    const float* vb = vertBase(v + 1);
                    n1x = vb[pvi1 * 3]; n1y = vb[pvi1 * 3 + 1]; n1z = vb[pvi1 * 3 + 2];
                    n2x = vb[pvi2 * 3]; n2y = vb[pvi2 * 3 + 1]; n2z = vb[pvi2 * 3 + 2];
                    if (has3) {
                        n3x = vb[pvi3 * 3]; n3y = vb[pvi3 * 3 + 1]; n3z = vb[pvi3 * 3 + 2];
                    }
                }
                if (q == 7) {                 // volume v complete
                    float acc = acc1 + acc2 + acc3;
                    #pragma unroll
                    for (int off = 32; off; off >>= 1)
                        acc += __shfl_down(acc, off);
                    if (lane == 0) wsum[wv - 2] = acc;
                }
            }
            __syncthreads();
        }

        p1x = n1x; p1y = n1y; p1z = n1z; p2x = n2x; p2y = n2y; p2z = n2z;
        p3x = n3x; p3y = n3y; p3z = n3z;
    }

    // final volume's atomic
    if (!producer && ct == 0) {
        float tot = wsum[0] + wsum[1] + wsum[2] + wsum[3] + wsum[4] + wsum[5];
        atomicAdd(loss + bOf(VPB - 1), tot * 0.25f);
    }
}

extern "C" void kernel_launch(void* const* d_in, const int* in_sizes, int n_in,
                              void* d_out, int out_size, void* d_ws, size_t ws_size,
                              hipStream_t stream) {
    const float* vertices = (const float*)d_in[0];
    const float* phiR     = (const float*)d_in[1];
    const float* phiL     = (const float*)d_in[2];
    const int*   seg      = (const int*)d_in[3];
    float* loss = (float*)d_out;

    hipMemsetAsync(d_out, 0, (size_t)out_size * sizeof(float), stream);

    sample_kernel<<<NBLK, 512, 0, stream>>>(vertices, seg, phiR, phiL, loss);
}

// Round 19
// 101.627 us; speedup vs baseline: 1.6619x; 1.6619x over previous
//
#include <hip/hip_runtime.h>

#define NVV   778
#define NSEG  16
#define SEGSZ 49
#define GRIDN 32
#define BATCH 128
#define NPTS  784
#define VOLSZ (GRIDN * GRIDN * GRIDN)  // 32768 floats = 128 KB
#define NBLK  512                       // 2 blocks/CU
#define VPB   8                         // volumes per block
#define PFLT  8192                      // floats per piece (8 slabs, 32 KB)

typedef float f4v __attribute__((ext_vector_type(4)));
#define NTLD(p) __builtin_nontemporal_load((const f4v*)(p))

// 32 KB piece staged by 4 producer waves (wv 0-3): 8 KB/wave, 8 x dwordx4
// nt loads (no L2/L3 allocation — R15's proven +5% win).
#define STAGE(DST, SRC) { \
    const float* s_ = (SRC) + (wv << 11) + (lane << 2); \
    float*       d_ = (DST) + (wv << 11) + (lane << 2); \
    f4v c0 = NTLD(s_ + 0 * 256); \
    f4v c1 = NTLD(s_ + 1 * 256); \
    f4v c2 = NTLD(s_ + 2 * 256); \
    f4v c3 = NTLD(s_ + 3 * 256); \
    f4v c4 = NTLD(s_ + 4 * 256); \
    f4v c5 = NTLD(s_ + 5 * 256); \
    f4v c6 = NTLD(s_ + 6 * 256); \
    f4v c7 = NTLD(s_ + 7 * 256); \
    *(f4v*)(d_ + 0 * 256) = c0; \
    *(f4v*)(d_ + 1 * 256) = c1; \
    *(f4v*)(d_ + 2 * 256) = c2; \
    *(f4v*)(d_ + 3 * 256) = c3; \
    *(f4v*)(d_ + 4 * 256) = c4; \
    *(f4v*)(d_ + 5 * 256) = c5; \
    *(f4v*)(d_ + 6 * 256) = c6; \
    *(f4v*)(d_ + 7 * 256) = c7; }

// 2x2 xy-taps within one z-slab
__device__ __forceinline__ float tapxy(const float* slab, int x0, int y0,
                                       float wx, float wy)
{
    float s = 0.f;
    #pragma unroll
    for (int dy = 0; dy < 2; ++dy) {
        int yy = y0 + dy;
        if (yy < 0 || yy >= GRIDN) continue;
        float wyv = dy ? wy : 1.f - wy;
        const float* row = slab + yy * GRIDN;
        #pragma unroll
        for (int dx = 0; dx < 2; ++dx) {
            int xx = x0 + dx;
            if (xx < 0 || xx >= GRIDN) continue;
            s += wyv * (dx ? wx : 1.f - wx) * row[xx];
        }
    }
    return s;
}

// point J's taps that land in piece Q (slab s belongs to piece s>>3)
#define TAP1(Q, BASE, J) \
    if (a##J) { \
        if (z##J >= 0 && (z##J >> 3) == (Q)) \
            acc##J += (1.f - w##J##z) * tapxy((BASE) + (z##J - 8 * (Q)) * 1024, x##J, y##J, w##J##x, w##J##y); \
        if ((z##J + 1) <= 31 && ((z##J + 1) >> 3) == (Q)) \
            acc##J += w##J##z * tapxy((BASE) + (z##J + 1 - 8 * (Q)) * 1024, x##J, y##J, w##J##x, w##J##y); \
    }
#define TAPALL(Q, BASE) \
    TAP1(Q, BASE, 1) TAP1(Q, BASE, 2) TAP1(Q, BASE, 3) \
    if (has4) { TAP1(Q, BASE, 4) }

#define SETUP(J, PX, PY, PZ) { \
    float fx = ((PX) - b4.x) * b4.w * 15.5f + 15.5f; \
    float fy = ((PY) - b4.y) * b4.w * 15.5f + 15.5f; \
    float fz = ((PZ) - b4.z) * b4.w * 15.5f + 15.5f; \
    a##J = (fx > -1.f && fx < 32.f && fy > -1.f && fy < 32.f && \
            fz > -1.f && fz < 32.f); \
    float xf = floorf(fx), yf = floorf(fy), zf = floorf(fz); \
    w##J##x = fx - xf; w##J##y = fy - yf; w##J##z = fz - zf; \
    x##J = (int)xf; y##J = (int)yf; z##J = (int)zf; acc##J = 0.f; }

// Persistent: 512 blocks x 512 threads -> 2 independent blocks per CU
// (~66 KB LDS each). Cross-block TLP hides each block's barrier drain.
// Waves 0-3 stage 32 KB pieces with nt loads; waves 4-7 tap the previous
// piece. 4 phases/volume, 8 volumes/block, one deferred atomic/volume.
// R18 lesson: 4 blocks/CU (VGPR cap 64) spills consumer state -> 100 MB
// scratch traffic; 2 blocks/CU (cap 128) is the TLP limit here.
__global__ __launch_bounds__(512, 4) void sample_kernel(
    const float* __restrict__ vertices, const int* __restrict__ seg,
    const float* __restrict__ phiR, const float* __restrict__ phiL,
    float* __restrict__ loss)
{
    __shared__ __align__(16) float P0[PFLT];
    __shared__ __align__(16) float P1[PFLT];
    __shared__ float4 sbox[VPB];
    __shared__ float wsum[4];

    const int tid  = threadIdx.x;
    const int bx   = blockIdx.x;
    const int k    = bx & (NSEG - 1);    // constant per block (512 % 16 == 0)
    const int wv   = tid >> 6;           // 0..3 producers, 4..7 consumers
    const int lane = tid & 63;
    const bool producer = (wv < 4);
    const int ct   = tid - 256;          // consumer thread id [0,256)

    auto phiPtr = [&](int it) {
        int vid  = bx + NBLK * it;
        int b    = (vid >> 4) & (BATCH - 1);
        int pass = vid >> 11;            // NSEG*BATCH = 2048
        return (pass == 0 ? phiR : phiL) + ((size_t)k * BATCH + b) * VOLSZ;
    };
    auto vertBase = [&](int it) {
        int vid  = bx + NBLK * it;
        int b    = (vid >> 4) & (BATCH - 1);
        int srcS = (vid >> 11) == 0 ? 1 : 0;   // pass0 samples LEFT verts
        return vertices + ((size_t)b * 2 + srcS) * NVV * 3;
    };
    auto bOf = [&](int it) { return ((bx + NBLK * it) >> 4) & (BATCH - 1); };

    // ---- prologue ----
    int pvi1 = 0, pvi2 = 0, pvi3 = 0, pvi4 = 0;
    bool has4 = false;
    if (!producer) {
        pvi1 = seg[ct];
        pvi2 = seg[ct + 256];
        pvi3 = seg[ct + 512];
        has4 = (ct + 768) < NPTS;        // ct < 16
        pvi4 = has4 ? seg[ct + 768] : 0;
    }

    // boxes: wave wv computes volume wv's box (8 waves = VPB)
    {
        int vidw    = bx + NBLK * wv;
        int bbw     = (vidw >> 4) & (BATCH - 1);
        int boxSide = ((vidw >> 11) == 0) ? 0 : 1;   // opposite of sampled
        bool bact   = lane < SEGSZ;
        int bvi     = bact ? seg[k * SEGSZ + lane] : 0;
        const float* bvp = vertices + (((size_t)bbw * 2 + boxSide) * NVV + bvi) * 3;
        float x = bvp[0], y = bvp[1], z = bvp[2];
        float mnx = bact ? x : 1e30f, mxx = bact ? x : -1e30f;
        float mny = bact ? y : 1e30f, mxy = bact ? y : -1e30f;
        float mnz = bact ? z : 1e30f, mxz = bact ? z : -1e30f;
        #pragma unroll
        for (int m = 32; m; m >>= 1) {
            mnx = fminf(mnx, __shfl_xor(mnx, m));
            mxx = fmaxf(mxx, __shfl_xor(mxx, m));
            mny = fminf(mny, __shfl_xor(mny, m));
            mxy = fmaxf(mxy, __shfl_xor(mxy, m));
            mnz = fminf(mnz, __shfl_xor(mnz, m));
            mxz = fmaxf(mxz, __shfl_xor(mxz, m));
        }
        if (lane == 0) {
            float ext = fmaxf(fmaxf(mxx - mnx, mxy - mny), mxz - mnz);
            sbox[wv] = make_float4(0.5f * (mnx + mxx), 0.5f * (mny + mxy),
                                   0.5f * (mnz + mxz), 1.0f / (0.55f * ext));
        }
    }

    // volume-0 coords (consumers); producers stage piece 0 -> P0
    float p1x = 0.f, p1y = 0.f, p1z = 0.f, p2x = 0.f, p2y = 0.f, p2z = 0.f;
    float p3x = 0.f, p3y = 0.f, p3z = 0.f, p4x = 0.f, p4y = 0.f, p4z = 0.f;
    if (producer) {
        STAGE(P0, phiPtr(0))
    } else {
        const float* vb = vertBase(0);
        p1x = vb[pvi1 * 3]; p1y = vb[pvi1 * 3 + 1]; p1z = vb[pvi1 * 3 + 2];
        p2x = vb[pvi2 * 3]; p2y = vb[pvi2 * 3 + 1]; p2z = vb[pvi2 * 3 + 2];
        p3x = vb[pvi3 * 3]; p3y = vb[pvi3 * 3 + 1]; p3z = vb[pvi3 * 3 + 2];
        if (has4) {
            p4x = vb[pvi4 * 3]; p4y = vb[pvi4 * 3 + 1]; p4z = vb[pvi4 * 3 + 2];
        }
    }
    __syncthreads();   // P0 resident; sbox visible

    float n1x = 0.f, n1y = 0.f, n1z = 0.f, n2x = 0.f, n2y = 0.f, n2z = 0.f;
    float n3x = 0.f, n3y = 0.f, n3z = 0.f, n4x = 0.f, n4y = 0.f, n4z = 0.f;

    for (int v = 0; v < VPB; ++v) {
        const bool more = (v + 1 < VPB);
        bool a1 = false, a2 = false, a3 = false, a4 = false;
        int x1, y1, z1, x2, y2, z2, x3, y3, z3, x4, y4, z4;
        float w1x, w1y, w1z, w2x, w2y, w2z, w3x, w3y, w3z, w4x, w4y, w4z;
        float acc1 = 0.f, acc2 = 0.f, acc3 = 0.f, acc4 = 0.f;

        // ===== phase 0: stage piece 1 -> P1; tap piece 0 in P0 =====
        if (producer) {
            STAGE(P1, phiPtr(v) + PFLT)
        } else {
            if (v > 0 && ct == 0) {      // deferred atomic for volume v-1
                float tot = wsum[0] + wsum[1] + wsum[2] + wsum[3];
                atomicAdd(loss + bOf(v - 1), tot * 0.25f);
            }
            float4 b4 = sbox[v];
            SETUP(1, p1x, p1y, p1z)
            SETUP(2, p2x, p2y, p2z)
            SETUP(3, p3x, p3y, p3z)
            if (has4) { SETUP(4, p4x, p4y, p4z) }
            TAPALL(0, P0)
        }
        __syncthreads();

        // ===== phase 1: stage piece 2 -> P0; tap piece 1 in P1 =====
        if (producer) {
            STAGE(P0, phiPtr(v) + 2 * PFLT)
        } else {
            TAPALL(1, P1)
        }
        __syncthreads();

        // ===== phase 2: stage piece 3 -> P1; tap piece 2 in P0 =====
        if (producer) {
            STAGE(P1, phiPtr(v) + 3 * PFLT)
        } else {
            TAPALL(2, P0)
            if (more) {                  // next volume's coords (scattered)
                const float* vb = vertBase(v + 1);
                n1x = vb[pvi1 * 3]; n1y = vb[pvi1 * 3 + 1]; n1z = vb[pvi1 * 3 + 2];
                n2x = vb[pvi2 * 3]; n2y = vb[pvi2 * 3 + 1]; n2z = vb[pvi2 * 3 + 2];
                n3x = vb[pvi3 * 3]; n3y = vb[pvi3 * 3 + 1]; n3z = vb[pvi3 * 3 + 2];
                if (has4) {
                    n4x = vb[pvi4 * 3]; n4y = vb[pvi4 * 3 + 1]; n4z = vb[pvi4 * 3 + 2];
                }
            }
        }
        __syncthreads();

        // ===== phase 3: stage piece 0 of v+1 -> P0; tap piece 3 in P1 ==
        if (producer) {
            if (more) { STAGE(P0, phiPtr(v + 1)) }
        } else {
            TAPALL(3, P1)
            float acc = acc1 + acc2 + acc3 + acc4;
            #pragma unroll
            for (int off = 32; off; off >>= 1)
                acc += __shfl_down(acc, off);
            if (lane == 0) wsum[wv - 4] = acc;
        }
        __syncthreads();   // P0 (next) resident; P1 consumed; wsum visible

        p1x = n1x; p1y = n1y; p1z = n1z; p2x = n2x; p2y = n2y; p2z = n2z;
        p3x = n3x; p3y = n3y; p3z = n3z; p4x = n4x; p4y = n4y; p4z = n4z;
    }

    // final volume's atomic
    if (!producer && ct == 0) {
        float tot = wsum[0] + wsum[1] + wsum[2] + wsum[3];
        atomicAdd(loss + bOf(VPB - 1), tot * 0.25f);
    }
}

extern "C" void kernel_launch(void* const* d_in, const int* in_sizes, int n_in,
                              void* d_out, int out_size, void* d_ws, size_t ws_size,
                              hipStream_t stream) {
    const float* vertices = (const float*)d_in[0];
    const float* phiR     = (const float*)d_in[1];
    const float* phiL     = (const float*)d_in[2];
    const int*   seg      = (const int*)d_in[3];
    float* loss = (float*)d_out;

    hipMemsetAsync(d_out, 0, (size_t)out_size * sizeof(float), stream);

    sample_kernel<<<NBLK, 512, 0, stream>>>(vertices, seg, phiR, phiL, loss);
}